// Round 4
// baseline (1694.854 us; speedup 1.0000x reference)
//
#include <hip/hip_runtime.h>
#include <math.h>

#define BB 32
#define TT 2048
#define HH 128

// LDS-only barrier: waits LDS ops (lgkmcnt), leaves global loads/stores in
// flight across the barrier.
#define LDS_BARRIER() asm volatile("s_waitcnt lgkmcnt(0)\n\ts_barrier" ::: "memory")

// DPP quad_perm helper. CTRL = p0|p1<<2|p2<<4|p3<<6. xor1=0xB1, xor2=0x4E,
// broadcast lane q within quad = q*0x55.
#define QPERM_F(v, CTRL)                                                      \
  __int_as_float(__builtin_amdgcn_update_dpp(                                 \
      0, __float_as_int(v), (CTRL), 0xF, 0xF, true))

// ---------------------------------------------------------------------------
// proj kernel: out[r, :] = src_row(r) @ W + bias
// ---------------------------------------------------------------------------
template <bool GATHER>
__global__ __launch_bounds__(256) void proj_kernel(
    const float* __restrict__ src, const int* __restrict__ tokens,
    const float* __restrict__ W, const float* __restrict__ bias,
    float* __restrict__ out) {
  const int tid = threadIdx.x;
  const int jj = tid & 31;
  const int rr = tid >> 5;
  const int base = blockIdx.x * 64;

  __shared__ __align__(16) float srow[64][HH];
  __shared__ int stok[64];

  if (GATHER) {
    if (tid < 64) stok[tid] = tokens[base + tid];
    __syncthreads();
  }

#pragma unroll
  for (int i = 0; i < 8; ++i) {
    int idx = tid + i * 256;
    int row = idx >> 5;
    int c4 = idx & 31;
    const float* s = GATHER ? (src + (size_t)stok[row] * HH)
                            : (src + (size_t)(base + row) * HH);
    *(float4*)&srow[row][c4 * 4] = *(const float4*)&s[c4 * 4];
  }
  __syncthreads();

  float4 b4 = *(const float4*)&bias[jj * 4];
  float4 acc[8];
#pragma unroll
  for (int i = 0; i < 8; ++i) acc[i] = b4;

  for (int k = 0; k < HH; ++k) {
    float4 w4 = *(const float4*)&W[k * HH + jj * 4];
#pragma unroll
    for (int i = 0; i < 8; ++i) {
      float e = srow[rr * 8 + i][k];
      acc[i].x += e * w4.x;
      acc[i].y += e * w4.y;
      acc[i].z += e * w4.z;
      acc[i].w += e * w4.w;
    }
  }

#pragma unroll
  for (int i = 0; i < 8; ++i) {
    int row = base + rr * 8 + i;
    *(float4*)&out[(size_t)row * HH + jj * 4] = acc[i];
  }
}

// ---------------------------------------------------------------------------
// rnn kernel v4: quad-split dot + 2-column reuse (halves LDS delivered bytes,
// which round-3 counters showed to be the binding resource: 64KB/step at
// ~85B/cyc == the measured 748 cyc/step).
// 256 threads (4 waves), one block per batch. Thread (q = tid>>2, p = tid&3)
// owns columns {q, q+64}, k-slice p (k = 16i+4p+r) -> 64 weight VGPRs.
// Per step: 8x ds_read_b128 (32 floats, read ONCE, used for both columns),
// 64 FMAs, 2x DPP quad-reduce, 2x tanh. h published via double-buffered LDS,
// one lgkm-only barrier per step. x loaded once per 4 steps (lane p holds
// rows t0+p), DPP quad-broadcast per step. In-place (reads [t0+4+p], writes
// [t]); per-column ownership -> no cross-thread aliasing.
// ---------------------------------------------------------------------------
__global__ __launch_bounds__(256) void rnn_kernel(
    float* io, const float* __restrict__ Wh, const int* __restrict__ tokens) {
  const int b = blockIdx.x;
  const int tid = threadIdx.x;
  const int q = tid >> 2;    // column pair base: cols q and q+64
  const int p = tid & 3;     // k-slice 0..3
  const int lane = tid & 63;

  // 64 weights: w0/w1[c] <-> k = 16*(c>>2) + 4*p + (c&3), cols q / q+64.
  float w0[32], w1[32];
#pragma unroll
  for (int c = 0; c < 32; ++c) {
    int k = 16 * (c >> 2) + 4 * p + (c & 3);
    w0[c] = Wh[k * HH + q];
    w1[c] = Wh[k * HH + q + 64];
  }

  // Mask bitmask: lane l holds bits for t in [32l, 32l+32).
  const int* tok = tokens + b * TT;
  unsigned bits = 0;
#pragma unroll
  for (int i = 0; i < 8; ++i) {
    int4 tk = *(const int4*)&tok[lane * 32 + i * 4];
    bits |= (unsigned)(tk.x != 0) << (i * 4 + 0);
    bits |= (unsigned)(tk.y != 0) << (i * 4 + 1);
    bits |= (unsigned)(tk.z != 0) << (i * 4 + 2);
    bits |= (unsigned)(tk.w != 0) << (i * 4 + 3);
  }

  __shared__ __align__(16) float hs[2][HH];
  if (tid < HH) hs[0][tid] = 0.0f;

  float* xp = io + (size_t)b * TT * HH;

  float h0 = 0.0f, h1 = 0.0f;
  // lane p holds x rows t0+p of the current 4-step group, both columns.
  float xc0 = xp[(size_t)p * HH + q];
  float xc1 = xp[(size_t)p * HH + q + 64];
  LDS_BARRIER();

#define RNN_STEP(Q)                                                           \
  {                                                                           \
    const int t = t0 + (Q);                                                   \
    const float* hb = hs[t & 1];                                              \
    float a0 = 0.f, a1 = 0.f, a2 = 0.f, a3 = 0.f;                             \
    float c0 = 0.f, c1 = 0.f, c2 = 0.f, c3 = 0.f;                             \
    _Pragma("unroll") for (int i = 0; i < 8; ++i) {                           \
      float4 hv = *(const float4*)&hb[16 * i + 4 * p];                        \
      a0 += hv.x * w0[4 * i + 0];                                             \
      a1 += hv.y * w0[4 * i + 1];                                             \
      a2 += hv.z * w0[4 * i + 2];                                             \
      a3 += hv.w * w0[4 * i + 3];                                             \
      c0 += hv.x * w1[4 * i + 0];                                             \
      c1 += hv.y * w1[4 * i + 1];                                             \
      c2 += hv.z * w1[4 * i + 2];                                             \
      c3 += hv.w * w1[4 * i + 3];                                             \
    }                                                                         \
    float accA = (a0 + a1) + (a2 + a3);                                       \
    float accB = (c0 + c1) + (c2 + c3);                                       \
    accA += QPERM_F(accA, 0xB1);                                              \
    accA += QPERM_F(accA, 0x4E);                                              \
    accB += QPERM_F(accB, 0xB1);                                              \
    accB += QPERM_F(accB, 0x4E);                                              \
    float sA = accA + QPERM_F(xc0, (Q) * 0x55);                               \
    float sB = accB + QPERM_F(xc1, (Q) * 0x55);                               \
    unsigned word =                                                           \
        (unsigned)__builtin_amdgcn_readlane((int)bits, t >> 5);               \
    int m = (word >> (t & 31)) & 1;                                           \
    float eA = __expf(-2.0f * fabsf(sA));                                     \
    float thA = copysignf((1.0f - eA) * __builtin_amdgcn_rcpf(1.0f + eA), sA);\
    float eB = __expf(-2.0f * fabsf(sB));                                     \
    float thB = copysignf((1.0f - eB) * __builtin_amdgcn_rcpf(1.0f + eB), sB);\
    h0 = m ? thA : h0;                                                        \
    h1 = m ? thB : h1;                                                        \
    if (p == 0) {                                                             \
      xp[(size_t)t * HH + q] = h0;                                            \
      hs[(t + 1) & 1][q] = h0;                                                \
    } else if (p == 1) {                                                      \
      xp[(size_t)t * HH + q + 64] = h1;                                       \
      hs[(t + 1) & 1][q + 64] = h1;                                           \
    }                                                                         \
    LDS_BARRIER();                                                            \
  }

  for (int t0 = 0; t0 < TT; t0 += 4) {
    float xn0 = 0.0f, xn1 = 0.0f;
    if (t0 + 4 + p < TT) {
      xn0 = xp[(size_t)(t0 + 4 + p) * HH + q];
      xn1 = xp[(size_t)(t0 + 4 + p) * HH + q + 64];
    }
    RNN_STEP(0)
    RNN_STEP(1)
    RNN_STEP(2)
    RNN_STEP(3)
    xc0 = xn0;
    xc1 = xn1;
  }
#undef RNN_STEP
}

extern "C" void kernel_launch(void* const* d_in, const int* in_sizes, int n_in,
                              void* d_out, int out_size, void* d_ws,
                              size_t ws_size, hipStream_t stream) {
  const int* tokens = (const int*)d_in[0];
  const float* emb = (const float*)d_in[1];
  const float* Wx0 = (const float*)d_in[2];
  const float* Wh0 = (const float*)d_in[3];
  const float* b0 = (const float*)d_in[4];
  const float* Wx1 = (const float*)d_in[5];
  const float* Wh1 = (const float*)d_in[6];
  const float* b1 = (const float*)d_in[7];
  float* out = (float*)d_out;
  float* ws = (float*)d_ws;  // 32 MB: xp0 -> ys0 (in-place)

  const int rows = BB * TT;            // 65536
  const int proj_blocks = rows / 64;   // 1024

  proj_kernel<true><<<proj_blocks, 256, 0, stream>>>(emb, tokens, Wx0, b0, ws);
  rnn_kernel<<<BB, 256, 0, stream>>>(ws, Wh0, tokens);
  proj_kernel<false><<<proj_blocks, 256, 0, stream>>>(ws, nullptr, Wx1, b1, out);
  rnn_kernel<<<BB, 256, 0, stream>>>(out, Wh1, tokens);
}